// Round 1
// baseline (526.937 us; speedup 1.0000x reference)
//
#include <hip/hip_runtime.h>
#include <cstdint>
#include <cstddef>

// ---------------------------------------------------------------------------
// MultiHeadAttention B=4,T=2048,E=1024,H=16,D=64 — bf16 MFMA implementation.
// Pipeline: cast qkv -> prep weights -> batched proj GEMM -> flash attention
//           -> output projection (+bias).
// All GEMM-shaped work uses the guide-verified gemm_bt structure:
//   16x16x32 bf16 MFMA, A frag A[m=lane&15][k=quad*8+j], B frag from K-major
//   rows, C/D col=lane&15 row=quad*4+reg. global_load_lds width=16 staging.
// ---------------------------------------------------------------------------

#define B_ 4
#define T_ 2048
#define E_ 1024
#define H_ 16
#define D_ 64
#define MROWS 8192            // B*T
#define MK    8388608         // MROWS*E
// softmax computed base-2: logits * (log2(e)/sqrt(E))
#define SCALE_LOG2E 0.045084220027780106f

typedef unsigned short u16;
typedef unsigned int   u32;
typedef __attribute__((ext_vector_type(4))) float  f32x4;
typedef __attribute__((ext_vector_type(4))) u32    u32x4;
typedef __attribute__((ext_vector_type(8))) u16    u16x8;
typedef __attribute__((ext_vector_type(8))) __bf16 bf16x8;

typedef __attribute__((address_space(1))) void gvoid_t;
typedef __attribute__((address_space(3))) void lvoid_t;

__device__ __forceinline__ void async_load16(const void* g, void* l) {
  // direct-to-LDS DMA: dest = wave-uniform lds base + lane*16
  __builtin_amdgcn_global_load_lds((gvoid_t*)(uintptr_t)g, (lvoid_t*)l, 16, 0, 0);
}

__device__ __forceinline__ u16 f2bf(float f) {  // RNE f32 -> bf16
  u32 u = __builtin_bit_cast(u32, f);
  u = (u + 0x7FFFu + ((u >> 16) & 1u)) >> 16;
  return (u16)u;
}

__device__ __forceinline__ bf16x8 ldfrag(const u16* p) {  // 16B LDS read
  u32x4 t = *(const u32x4*)p;
  return __builtin_bit_cast(bf16x8, t);
}

__device__ __forceinline__ f32x4 mfma_bf16(bf16x8 a, bf16x8 b, f32x4 c) {
  return __builtin_amdgcn_mfma_f32_16x16x32_bf16(a, b, c, 0, 0, 0);
}

// ---------------------------------------------------------------------------
// Kernel 1: cast q,k,v fp32 -> bf16 (z = 0:q, 1:k, 2:v). 8 elems/thread.
// ---------------------------------------------------------------------------
__global__ __launch_bounds__(256) void cast_qkv_kernel(
    const float* __restrict__ q, const float* __restrict__ k,
    const float* __restrict__ v, u16* __restrict__ dst) {
  const int z = blockIdx.y;
  const float* src = (z == 0) ? q : (z == 1) ? k : v;
  u16* out = dst + (size_t)z * MK;
  size_t i0 = ((size_t)blockIdx.x * 256 + threadIdx.x) * 8;
  float4 a = *(const float4*)(src + i0);
  float4 b = *(const float4*)(src + i0 + 4);
  u16x8 o;
  o[0] = f2bf(a.x); o[1] = f2bf(a.y); o[2] = f2bf(a.z); o[3] = f2bf(a.w);
  o[4] = f2bf(b.x); o[5] = f2bf(b.y); o[6] = f2bf(b.z); o[7] = f2bf(b.w);
  *(u16x8*)(out + i0) = o;
}

// ---------------------------------------------------------------------------
// Kernel 2: weights. z<3: Wt[z][j=h*64+d][e] = W[h][e][d] (bf16, K-contiguous
// rows for gemm_bt). z==3: Wp direct cast (already [j][e]).
// ---------------------------------------------------------------------------
__global__ __launch_bounds__(256) void prep_weights_kernel(
    const float* __restrict__ Wq, const float* __restrict__ Wk,
    const float* __restrict__ Wv, const float* __restrict__ Wp,
    u16* __restrict__ dstW, u16* __restrict__ dstWp) {
  const int z = blockIdx.y;
  const int t = blockIdx.x * 256 + threadIdx.x;  // 0 .. E*E-1
  if (z == 3) { dstWp[t] = f2bf(Wp[t]); return; }
  const float* W = (z == 0) ? Wq : (z == 1) ? Wk : Wv;
  const int j = t >> 10, e = t & 1023;
  const int h = j >> 6, d = j & 63;
  dstW[(size_t)z * (E_ * E_) + t] = f2bf(W[h * (E_ * D_) + e * D_ + d]);
}

// ---------------------------------------------------------------------------
// Kernel 3/5: gemm_bt  C[i,j] = sum_k A[i,k]*Bt[j,k]  (8192x1024x1024)
// 128x128 tile, BK=32, 4 waves (2x2 of 64x64), 16 MFMA / wave / K-step.
// FINAL=0: bf16 C (proj, z batches). FINAL=1: fp32 C + bias.
// ---------------------------------------------------------------------------
template <int FINAL>
__global__ __launch_bounds__(256) void gemm_bt_kernel(
    const u16* __restrict__ Abase, const u16* __restrict__ Btbase,
    u16* __restrict__ Cb, float* __restrict__ Cf,
    const float* __restrict__ bias) {
  constexpr int Md = 8192, Nd = 1024, Kd = 1024;
  __shared__ __align__(16) u16 As[128 * 32];
  __shared__ __align__(16) u16 Bs[128 * 32];
  const int tid = threadIdx.x;
  const int wave = tid >> 6, lane = tid & 63;
  const int l16 = lane & 15, quad = lane >> 4;
  const int z = blockIdx.z;
  const u16* A  = Abase  + (size_t)z * Md * Kd;
  const u16* Bt = Btbase + (size_t)z * Nd * Kd;
  const int tm = blockIdx.x * 128, tn = blockIdx.y * 128;
  const int wm = (wave >> 1) * 64, wn = (wave & 1) * 64;

  f32x4 acc[4][4];
#pragma unroll
  for (int i = 0; i < 4; ++i)
#pragma unroll
    for (int j = 0; j < 4; ++j) acc[i][j] = f32x4{0.f, 0.f, 0.f, 0.f};

  // staging: chunk c = tid (rows tm+c>>2, 16B seg c&3) and c = 256+tid
  const int row0 = tid >> 2, seg = tid & 3;
  const u16* Ag0 = A  + (size_t)(tm + row0) * Kd + seg * 8;
  const u16* Ag1 = Ag0 + (size_t)64 * Kd;
  const u16* Bg0 = Bt + (size_t)(tn + row0) * Kd + seg * 8;
  const u16* Bg1 = Bg0 + (size_t)64 * Kd;
  char* AsB = (char*)&As[0];
  char* BsB = (char*)&Bs[0];
  const int wbase = wave * 1024;

  for (int kt = 0; kt < Kd / 32; ++kt) {
    async_load16(Ag0, AsB + wbase);
    async_load16(Ag1, AsB + 4096 + wbase);
    async_load16(Bg0, BsB + wbase);
    async_load16(Bg1, BsB + 4096 + wbase);
    Ag0 += 32; Ag1 += 32; Bg0 += 32; Bg1 += 32;
    __syncthreads();  // drains vmcnt -> tiles resident
    bf16x8 af[4], bfr[4];
#pragma unroll
    for (int i = 0; i < 4; ++i) {
      af[i]  = ldfrag(&As[(wm + i * 16 + l16) * 32 + quad * 8]);
      bfr[i] = ldfrag(&Bs[(wn + i * 16 + l16) * 32 + quad * 8]);
    }
#pragma unroll
    for (int mi = 0; mi < 4; ++mi)
#pragma unroll
      for (int ni = 0; ni < 4; ++ni)
        acc[mi][ni] = mfma_bf16(af[mi], bfr[ni], acc[mi][ni]);
    __syncthreads();  // all reads done before restage
  }

  if (FINAL) {
    float bv[4];
#pragma unroll
    for (int ni = 0; ni < 4; ++ni) bv[ni] = bias[tn + wn + ni * 16 + l16];
#pragma unroll
    for (int mi = 0; mi < 4; ++mi)
#pragma unroll
      for (int r = 0; r < 4; ++r) {
        const int row = tm + wm + mi * 16 + quad * 4 + r;
        float* cp = Cf + (size_t)row * Nd + tn + wn;
#pragma unroll
        for (int ni = 0; ni < 4; ++ni)
          cp[ni * 16 + l16] = acc[mi][ni][r] + bv[ni];
      }
  } else {
    u16* C = Cb + (size_t)z * Md * Nd;
#pragma unroll
    for (int mi = 0; mi < 4; ++mi)
#pragma unroll
      for (int r = 0; r < 4; ++r) {
        const int row = tm + wm + mi * 16 + quad * 4 + r;
        u16* cp = C + (size_t)row * Nd + tn + wn;
#pragma unroll
        for (int ni = 0; ni < 4; ++ni)
          cp[ni * 16 + l16] = f2bf(acc[mi][ni][r]);
      }
  }
}

// ---------------------------------------------------------------------------
// Kernel 4: causal flash attention. Block = (qt, b*h), 256 thr (4 waves).
// BM=128 Q rows (wave w owns rows w*32..w*32+31), BN=64 K rows per iter.
// Qs/Ks: [ks][rows][32] half-tiles (global_load_lds-compatible, stride 32).
// Vts: V^T [d][j] stride 72 (2-way-conflict-free b128 reads, 16B aligned).
// Ps : P  [row][j] stride 72 (C-layout -> A-layout LDS round trip).
// ---------------------------------------------------------------------------
__global__ __launch_bounds__(256) void attn_kernel(
    const u16* __restrict__ Xq, const u16* __restrict__ Xk,
    const u16* __restrict__ Xv, u16* __restrict__ Xo) {
  const int qt = blockIdx.x;           // 0..15
  const int bh = blockIdx.y;           // 0..63
  const int b = bh >> 4, h = bh & 15;
  const int tid = threadIdx.x, wave = tid >> 6, lane = tid & 63;
  const int l16 = lane & 15, quad = lane >> 4;

  __shared__ __align__(16) u16 Qs[2 * 128 * 32];  // 16 KB
  __shared__ __align__(16) u16 Ks[2 * 64 * 32];   //  8 KB
  __shared__ __align__(16) u16 Vts[64 * 72];      //  9 KB
  __shared__ __align__(16) u16 Ps[128 * 72];      // 18 KB

  const size_t base = (size_t)b * T_ * E_ + h * 64;
  const u16* Qp = Xq + base + (size_t)qt * 128 * E_;
  const u16* Kp = Xk + base;
  const u16* Vp = Xv + base;

  // ---- stage Q once: 16 calls x 64 lanes x 16B ----
  char* QsB = (char*)&Qs[0];
#pragma unroll
  for (int i = 0; i < 4; ++i) {
    const int call = wave * 4 + i;          // 0..15
    const int ks = call >> 3, rb = (call & 7) * 16;
    const int row = rb + (lane >> 2), k8 = lane & 3;
    async_load16(Qp + (size_t)row * E_ + ks * 32 + k8 * 8,
                 QsB + ks * 8192 + rb * 64);
  }

  f32x4 o_acc[2][4];
#pragma unroll
  for (int mi = 0; mi < 2; ++mi)
#pragma unroll
    for (int di = 0; di < 4; ++di) o_acc[mi][di] = f32x4{0.f, 0.f, 0.f, 0.f};
  float mrow[2][4], lrow[2][4];
#pragma unroll
  for (int mi = 0; mi < 2; ++mi)
#pragma unroll
    for (int r = 0; r < 4; ++r) { mrow[mi][r] = -INFINITY; lrow[mi][r] = 0.f; }

  char* KsB = (char*)&Ks[0];
  const int kt_end = 2 * qt + 1;
  for (int kt = 0; kt <= kt_end; ++kt) {
    // ---- stage K (async, half-tiles) ----
#pragma unroll
    for (int i = 0; i < 2; ++i) {
      const int call = wave + i * 4;        // 0..7
      const int ks = call >> 2, rb = (call & 3) * 16;
      const int row = rb + (lane >> 2), k8 = lane & 3;
      async_load16(Kp + (size_t)(kt * 64 + row) * E_ + ks * 32 + k8 * 8,
                   KsB + ks * 4096 + rb * 64);
    }
    // ---- stage V transposed via registers ----
#pragma unroll
    for (int i = 0; i < 2; ++i) {
      const int dseg = wave + i * 4;        // 0..7
      union { u32x4 v; u16 s[8]; } t;
      t.v = *(const u32x4*)(Vp + (size_t)(kt * 64 + lane) * E_ + dseg * 8);
#pragma unroll
      for (int ii = 0; ii < 8; ++ii)
        Vts[(dseg * 8 + ii) * 72 + lane] = t.s[ii];
    }
    __syncthreads();  // K/V (and first-iter Q) resident

    // ---- S = Q K^T ----
    bf16x8 qf[2][2], kf[4][2];
#pragma unroll
    for (int mi = 0; mi < 2; ++mi)
#pragma unroll
      for (int ks = 0; ks < 2; ++ks)
        qf[mi][ks] = ldfrag(&Qs[ks * 4096 + (wave * 32 + mi * 16 + l16) * 32 + quad * 8]);
#pragma unroll
    for (int ni = 0; ni < 4; ++ni)
#pragma unroll
      for (int ks = 0; ks < 2; ++ks)
        kf[ni][ks] = ldfrag(&Ks[ks * 2048 + (ni * 16 + l16) * 32 + quad * 8]);

    f32x4 sa[2][4];
#pragma unroll
    for (int mi = 0; mi < 2; ++mi)
#pragma unroll
      for (int ni = 0; ni < 4; ++ni) {
        f32x4 s = f32x4{0.f, 0.f, 0.f, 0.f};
        s = mfma_bf16(qf[mi][0], kf[ni][0], s);
        s = mfma_bf16(qf[mi][1], kf[ni][1], s);
        sa[mi][ni] = s;
      }

    // ---- online softmax (base-2) ----
    const int mask_on = (kt >= 2 * qt);
#pragma unroll
    for (int mi = 0; mi < 2; ++mi) {
      const int grow0 = qt * 128 + wave * 32 + mi * 16 + quad * 4;
#pragma unroll
      for (int ni = 0; ni < 4; ++ni) {
        const int gcol = kt * 64 + ni * 16 + l16;
#pragma unroll
        for (int r = 0; r < 4; ++r) {
          float s = sa[mi][ni][r] * SCALE_LOG2E;
          s = (mask_on && gcol > grow0 + r) ? -INFINITY : s;
          sa[mi][ni][r] = s;
        }
      }
#pragma unroll
      for (int r = 0; r < 4; ++r) {
        float mx = fmaxf(fmaxf(sa[mi][0][r], sa[mi][1][r]),
                         fmaxf(sa[mi][2][r], sa[mi][3][r]));
        mx = fmaxf(mx, __shfl_xor(mx, 1));
        mx = fmaxf(mx, __shfl_xor(mx, 2));
        mx = fmaxf(mx, __shfl_xor(mx, 4));
        mx = fmaxf(mx, __shfl_xor(mx, 8));
        const float mold = mrow[mi][r];
        const float mnew = fmaxf(mold, mx);
        const float alpha = exp2f(mold - mnew);   // 0 on first valid tile
        mrow[mi][r] = mnew;
        float sum = 0.f;
#pragma unroll
        for (int ni = 0; ni < 4; ++ni) {
          const float pv = exp2f(sa[mi][ni][r] - mnew);  // masked -> 0
          sa[mi][ni][r] = pv;
          sum += pv;
        }
        sum += __shfl_xor(sum, 1);
        sum += __shfl_xor(sum, 2);
        sum += __shfl_xor(sum, 4);
        sum += __shfl_xor(sum, 8);
        lrow[mi][r] = lrow[mi][r] * alpha + sum;
#pragma unroll
        for (int di = 0; di < 4; ++di) o_acc[mi][di][r] *= alpha;
      }
      // P: C-layout -> LDS [row][j] (only own wave's rows; no barrier needed)
#pragma unroll
      for (int ni = 0; ni < 4; ++ni)
#pragma unroll
        for (int r = 0; r < 4; ++r)
          Ps[(wave * 32 + mi * 16 + quad * 4 + r) * 72 + ni * 16 + l16] =
              f2bf(sa[mi][ni][r]);
    }

    // ---- O += P V ----
    bf16x8 pf[2][2], vf[4][2];
#pragma unroll
    for (int mi = 0; mi < 2; ++mi)
#pragma unroll
      for (int ks = 0; ks < 2; ++ks)
        pf[mi][ks] = ldfrag(&Ps[(wave * 32 + mi * 16 + l16) * 72 + ks * 32 + quad * 8]);
#pragma unroll
    for (int di = 0; di < 4; ++di)
#pragma unroll
      for (int ks = 0; ks < 2; ++ks)
        vf[di][ks] = ldfrag(&Vts[(di * 16 + l16) * 72 + ks * 32 + quad * 8]);
#pragma unroll
    for (int mi = 0; mi < 2; ++mi)
#pragma unroll
      for (int di = 0; di < 4; ++di) {
        o_acc[mi][di] = mfma_bf16(pf[mi][0], vf[di][0], o_acc[mi][di]);
        o_acc[mi][di] = mfma_bf16(pf[mi][1], vf[di][1], o_acc[mi][di]);
      }
    __syncthreads();  // done reading Ks/Vts before next-iter restage
  }

  // ---- epilogue: O /= l, write bf16 concat layout ----
  u16* Op = Xo + base + (size_t)qt * 128 * E_;
#pragma unroll
  for (int mi = 0; mi < 2; ++mi)
#pragma unroll
    for (int r = 0; r < 4; ++r) {
      const float inv = 1.0f / lrow[mi][r];
      const int row = wave * 32 + mi * 16 + quad * 4 + r;
#pragma unroll
      for (int di = 0; di < 4; ++di)
        Op[(size_t)row * E_ + di * 16 + l16] = f2bf(o_acc[mi][di][r] * inv);
    }
}

// ---------------------------------------------------------------------------
// Host launch. ws layout (bytes):
//   [0,          50331648) qkv bf16 (q,k,v)  -- later reused as Xo
//   [50331648,   56623104) Wt bf16 (Wq,Wk,Wv transformed)
//   [56623104,   58720256) Wp bf16
//   [58720256,  109051904) X bf16 (Xq,Xk,Xv)
// ---------------------------------------------------------------------------
extern "C" void kernel_launch(void* const* d_in, const int* in_sizes, int n_in,
                              void* d_out, int out_size, void* d_ws, size_t ws_size,
                              hipStream_t stream) {
  const float* k_in = (const float*)d_in[0];
  const float* q_in = (const float*)d_in[1];
  const float* v_in = (const float*)d_in[2];
  // d_in[3] = mask: exactly triu(k=1) causal -> computed analytically
  const float* Wk = (const float*)d_in[4];
  const float* Wq = (const float*)d_in[5];
  const float* Wv = (const float*)d_in[6];
  const float* Wp = (const float*)d_in[7];
  const float* bp = (const float*)d_in[8];
  float* out = (float*)d_out;

  char* ws = (char*)d_ws;
  u16* qkvb = (u16*)ws;
  u16* Wt   = (u16*)(ws + 50331648);
  u16* Wpb  = (u16*)(ws + 56623104);
  u16* X    = (u16*)(ws + 58720256);
  u16* Xo   = (u16*)ws;  // alias: qkv bf16 dead after proj GEMM

  cast_qkv_kernel<<<dim3(4096, 3), 256, 0, stream>>>(q_in, k_in, v_in, qkvb);
  prep_weights_kernel<<<dim3(4096, 4), 256, 0, stream>>>(Wq, Wk, Wv, Wp, Wt, Wpb);
  gemm_bt_kernel<0><<<dim3(64, 8, 3), 256, 0, stream>>>(qkvb, Wt, X, nullptr, nullptr);
  attn_kernel<<<dim3(16, 64), 256, 0, stream>>>(X, X + (size_t)MK, X + (size_t)2 * MK, Xo);
  gemm_bt_kernel<1><<<dim3(64, 8, 1), 256, 0, stream>>>(Xo, Wpb, nullptr, out, bp);
}

// Round 2
// 407.514 us; speedup vs baseline: 1.2931x; 1.2931x over previous
//
#include <hip/hip_runtime.h>
#include <cstdint>
#include <cstddef>

// ---------------------------------------------------------------------------
// MultiHeadAttention B=4,T=2048,E=1024,H=16,D=64 — bf16 MFMA implementation.
// Pipeline: cast qkv -> prep weights -> batched proj GEMM -> flash attention
//           -> output projection (+bias).
// R1 changes: attn kernel — Q in registers (LDS 52->35KB, 4 blocks/CU),
// longest-first balanced dispatch, row-sums via ones-MFMA (no sum shuffles).
// ---------------------------------------------------------------------------

#define B_ 4
#define T_ 2048
#define E_ 1024
#define H_ 16
#define D_ 64
#define MROWS 8192            // B*T
#define MK    8388608         // MROWS*E
// softmax computed base-2: logits * (log2(e)/sqrt(E))
#define SCALE_LOG2E 0.045084220027780106f

typedef unsigned short u16;
typedef unsigned int   u32;
typedef __attribute__((ext_vector_type(4))) float  f32x4;
typedef __attribute__((ext_vector_type(4))) u32    u32x4;
typedef __attribute__((ext_vector_type(8))) u16    u16x8;
typedef __attribute__((ext_vector_type(8))) __bf16 bf16x8;

typedef __attribute__((address_space(1))) void gvoid_t;
typedef __attribute__((address_space(3))) void lvoid_t;

__device__ __forceinline__ void async_load16(const void* g, void* l) {
  // direct-to-LDS DMA: dest = wave-uniform lds base + lane*16
  __builtin_amdgcn_global_load_lds((gvoid_t*)(uintptr_t)g, (lvoid_t*)l, 16, 0, 0);
}

__device__ __forceinline__ u16 f2bf(float f) {  // RNE f32 -> bf16
  u32 u = __builtin_bit_cast(u32, f);
  u = (u + 0x7FFFu + ((u >> 16) & 1u)) >> 16;
  return (u16)u;
}

__device__ __forceinline__ bf16x8 ldfrag(const u16* p) {  // 16B LDS read
  u32x4 t = *(const u32x4*)p;
  return __builtin_bit_cast(bf16x8, t);
}

__device__ __forceinline__ bf16x8 ldfrag_g(const u16* p) {  // 16B global read
  u32x4 t = *(const u32x4*)p;
  return __builtin_bit_cast(bf16x8, t);
}

__device__ __forceinline__ f32x4 mfma_bf16(bf16x8 a, bf16x8 b, f32x4 c) {
  return __builtin_amdgcn_mfma_f32_16x16x32_bf16(a, b, c, 0, 0, 0);
}

// ---------------------------------------------------------------------------
// Kernel 1: cast q,k,v fp32 -> bf16 (z = 0:q, 1:k, 2:v). 8 elems/thread.
// ---------------------------------------------------------------------------
__global__ __launch_bounds__(256) void cast_qkv_kernel(
    const float* __restrict__ q, const float* __restrict__ k,
    const float* __restrict__ v, u16* __restrict__ dst) {
  const int z = blockIdx.y;
  const float* src = (z == 0) ? q : (z == 1) ? k : v;
  u16* out = dst + (size_t)z * MK;
  size_t i0 = ((size_t)blockIdx.x * 256 + threadIdx.x) * 8;
  float4 a = *(const float4*)(src + i0);
  float4 b = *(const float4*)(src + i0 + 4);
  u16x8 o;
  o[0] = f2bf(a.x); o[1] = f2bf(a.y); o[2] = f2bf(a.z); o[3] = f2bf(a.w);
  o[4] = f2bf(b.x); o[5] = f2bf(b.y); o[6] = f2bf(b.z); o[7] = f2bf(b.w);
  *(u16x8*)(out + i0) = o;
}

// ---------------------------------------------------------------------------
// Kernel 2: weights. z<3: Wt[z][j=h*64+d][e] = W[h][e][d] (bf16, K-contiguous
// rows for gemm_bt). z==3: Wp direct cast (already [j][e]).
// ---------------------------------------------------------------------------
__global__ __launch_bounds__(256) void prep_weights_kernel(
    const float* __restrict__ Wq, const float* __restrict__ Wk,
    const float* __restrict__ Wv, const float* __restrict__ Wp,
    u16* __restrict__ dstW, u16* __restrict__ dstWp) {
  const int z = blockIdx.y;
  const int t = blockIdx.x * 256 + threadIdx.x;  // 0 .. E*E-1
  if (z == 3) { dstWp[t] = f2bf(Wp[t]); return; }
  const float* W = (z == 0) ? Wq : (z == 1) ? Wk : Wv;
  const int j = t >> 10, e = t & 1023;
  const int h = j >> 6, d = j & 63;
  dstW[(size_t)z * (E_ * E_) + t] = f2bf(W[h * (E_ * D_) + e * D_ + d]);
}

// ---------------------------------------------------------------------------
// Kernel 3/5: gemm_bt  C[i,j] = sum_k A[i,k]*Bt[j,k]  (8192x1024x1024)
// 128x128 tile, BK=32, 4 waves (2x2 of 64x64), 16 MFMA / wave / K-step.
// FINAL=0: bf16 C (proj, z batches). FINAL=1: fp32 C + bias.
// ---------------------------------------------------------------------------
template <int FINAL>
__global__ __launch_bounds__(256) void gemm_bt_kernel(
    const u16* __restrict__ Abase, const u16* __restrict__ Btbase,
    u16* __restrict__ Cb, float* __restrict__ Cf,
    const float* __restrict__ bias) {
  constexpr int Md = 8192, Nd = 1024, Kd = 1024;
  __shared__ __align__(16) u16 As[128 * 32];
  __shared__ __align__(16) u16 Bs[128 * 32];
  const int tid = threadIdx.x;
  const int wave = tid >> 6, lane = tid & 63;
  const int l16 = lane & 15, quad = lane >> 4;
  const int z = blockIdx.z;
  const u16* A  = Abase  + (size_t)z * Md * Kd;
  const u16* Bt = Btbase + (size_t)z * Nd * Kd;
  const int tm = blockIdx.x * 128, tn = blockIdx.y * 128;
  const int wm = (wave >> 1) * 64, wn = (wave & 1) * 64;

  f32x4 acc[4][4];
#pragma unroll
  for (int i = 0; i < 4; ++i)
#pragma unroll
    for (int j = 0; j < 4; ++j) acc[i][j] = f32x4{0.f, 0.f, 0.f, 0.f};

  // staging: chunk c = tid (rows tm+c>>2, 16B seg c&3) and c = 256+tid
  const int row0 = tid >> 2, seg = tid & 3;
  const u16* Ag0 = A  + (size_t)(tm + row0) * Kd + seg * 8;
  const u16* Ag1 = Ag0 + (size_t)64 * Kd;
  const u16* Bg0 = Bt + (size_t)(tn + row0) * Kd + seg * 8;
  const u16* Bg1 = Bg0 + (size_t)64 * Kd;
  char* AsB = (char*)&As[0];
  char* BsB = (char*)&Bs[0];
  const int wbase = wave * 1024;

  for (int kt = 0; kt < Kd / 32; ++kt) {
    async_load16(Ag0, AsB + wbase);
    async_load16(Ag1, AsB + 4096 + wbase);
    async_load16(Bg0, BsB + wbase);
    async_load16(Bg1, BsB + 4096 + wbase);
    Ag0 += 32; Ag1 += 32; Bg0 += 32; Bg1 += 32;
    __syncthreads();  // drains vmcnt -> tiles resident
    bf16x8 af[4], bfr[4];
#pragma unroll
    for (int i = 0; i < 4; ++i) {
      af[i]  = ldfrag(&As[(wm + i * 16 + l16) * 32 + quad * 8]);
      bfr[i] = ldfrag(&Bs[(wn + i * 16 + l16) * 32 + quad * 8]);
    }
#pragma unroll
    for (int mi = 0; mi < 4; ++mi)
#pragma unroll
      for (int ni = 0; ni < 4; ++ni)
        acc[mi][ni] = mfma_bf16(af[mi], bfr[ni], acc[mi][ni]);
    __syncthreads();  // all reads done before restage
  }

  if (FINAL) {
    float bv[4];
#pragma unroll
    for (int ni = 0; ni < 4; ++ni) bv[ni] = bias[tn + wn + ni * 16 + l16];
#pragma unroll
    for (int mi = 0; mi < 4; ++mi)
#pragma unroll
      for (int r = 0; r < 4; ++r) {
        const int row = tm + wm + mi * 16 + quad * 4 + r;
        float* cp = Cf + (size_t)row * Nd + tn + wn;
#pragma unroll
        for (int ni = 0; ni < 4; ++ni)
          cp[ni * 16 + l16] = acc[mi][ni][r] + bv[ni];
      }
  } else {
    u16* C = Cb + (size_t)z * Md * Nd;
#pragma unroll
    for (int mi = 0; mi < 4; ++mi)
#pragma unroll
      for (int r = 0; r < 4; ++r) {
        const int row = tm + wm + mi * 16 + quad * 4 + r;
        u16* cp = C + (size_t)row * Nd + tn + wn;
#pragma unroll
        for (int ni = 0; ni < 4; ++ni)
          cp[ni * 16 + l16] = f2bf(acc[mi][ni][r]);
      }
  }
}

// ---------------------------------------------------------------------------
// Kernel 4: causal flash attention. Block = (bh, y), qt = 15-y (longest
// blocks dispatch first -> balanced). 256 thr (4 waves).
// BM=128 Q rows (wave w owns rows w*32..w*32+31), BN=64 K rows per iter.
// Q fragments live in REGISTERS (loaded once from global; no Qs LDS).
// Ks : [ks][rows][32] half-tiles (global_load_lds layout, stride 32).
// Vts: V^T [d][j] stride 72 (16B-aligned b128 reads).
// Ps : P  [row][j] stride 72 (C-layout -> A-layout LDS round trip).
// Row sums via ones-vector MFMA (no sum shuffles).
// LDS total: 8 + 9 + 18 = 35 KB -> 4 blocks/CU @ 128 VGPR.
// ---------------------------------------------------------------------------
__global__ __launch_bounds__(256, 4) void attn_kernel(
    const u16* __restrict__ Xq, const u16* __restrict__ Xk,
    const u16* __restrict__ Xv, u16* __restrict__ Xo) {
  const int qt = 15 - blockIdx.y;      // longest-first
  const int bh = blockIdx.x;           // 0..63
  const int b = bh >> 4, h = bh & 15;
  const int tid = threadIdx.x, wave = tid >> 6, lane = tid & 63;
  const int l16 = lane & 15, quad = lane >> 4;

  __shared__ __align__(16) u16 Ks[2 * 64 * 32];   //  8 KB
  __shared__ __align__(16) u16 Vts[64 * 72];      //  9 KB
  __shared__ __align__(16) u16 Ps[128 * 72];      // 18 KB

  const size_t base = (size_t)b * T_ * E_ + h * 64;
  const u16* Qp = Xq + base + (size_t)qt * 128 * E_;
  const u16* Kp = Xk + base;
  const u16* Vp = Xv + base;

  // ---- Q fragments -> registers (one-time) ----
  bf16x8 qf[2][2];
#pragma unroll
  for (int mi = 0; mi < 2; ++mi)
#pragma unroll
    for (int ks = 0; ks < 2; ++ks)
      qf[mi][ks] = ldfrag_g(Qp + (size_t)(wave * 32 + mi * 16 + l16) * E_ +
                            ks * 32 + quad * 8);

  // ones B-frag for row-sum MFMA
  u16x8 ones_u;
#pragma unroll
  for (int i = 0; i < 8; ++i) ones_u[i] = 0x3F80;  // bf16 1.0
  const bf16x8 ones = __builtin_bit_cast(bf16x8, ones_u);

  f32x4 o_acc[2][4];
#pragma unroll
  for (int mi = 0; mi < 2; ++mi)
#pragma unroll
    for (int di = 0; di < 4; ++di) o_acc[mi][di] = f32x4{0.f, 0.f, 0.f, 0.f};
  float mrow[2][4], lrow[2][4];
#pragma unroll
  for (int mi = 0; mi < 2; ++mi)
#pragma unroll
    for (int r = 0; r < 4; ++r) { mrow[mi][r] = -INFINITY; lrow[mi][r] = 0.f; }

  char* KsB = (char*)&Ks[0];
  const int kt_end = 2 * qt + 1;
  for (int kt = 0; kt <= kt_end; ++kt) {
    // ---- stage K (async, half-tiles) ----
#pragma unroll
    for (int i = 0; i < 2; ++i) {
      const int call = wave + i * 4;        // 0..7
      const int ks = call >> 2, rb = (call & 3) * 16;
      const int row = rb + (lane >> 2), k8 = lane & 3;
      async_load16(Kp + (size_t)(kt * 64 + row) * E_ + ks * 32 + k8 * 8,
                   KsB + ks * 4096 + rb * 64);
    }
    // ---- stage V transposed via registers ----
#pragma unroll
    for (int i = 0; i < 2; ++i) {
      const int dseg = wave + i * 4;        // 0..7
      union { u32x4 v; u16 s[8]; } t;
      t.v = *(const u32x4*)(Vp + (size_t)(kt * 64 + lane) * E_ + dseg * 8);
#pragma unroll
      for (int ii = 0; ii < 8; ++ii)
        Vts[(dseg * 8 + ii) * 72 + lane] = t.s[ii];
    }
    __syncthreads();  // K/V resident

    // ---- S = Q K^T ----
    bf16x8 kf[4][2];
#pragma unroll
    for (int ni = 0; ni < 4; ++ni)
#pragma unroll
      for (int ks = 0; ks < 2; ++ks)
        kf[ni][ks] = ldfrag(&Ks[ks * 2048 + (ni * 16 + l16) * 32 + quad * 8]);

    f32x4 sa[2][4];
#pragma unroll
    for (int mi = 0; mi < 2; ++mi)
#pragma unroll
      for (int ni = 0; ni < 4; ++ni) {
        f32x4 s = f32x4{0.f, 0.f, 0.f, 0.f};
        s = mfma_bf16(qf[mi][0], kf[ni][0], s);
        s = mfma_bf16(qf[mi][1], kf[ni][1], s);
        sa[mi][ni] = s;
      }

    // ---- online softmax (base-2); sums deferred to ones-MFMA ----
    const int mask_on = (kt >= 2 * qt);
    float alpha[2][4];
#pragma unroll
    for (int mi = 0; mi < 2; ++mi) {
      const int grow0 = qt * 128 + wave * 32 + mi * 16 + quad * 4;
#pragma unroll
      for (int ni = 0; ni < 4; ++ni) {
        const int gcol = kt * 64 + ni * 16 + l16;
#pragma unroll
        for (int r = 0; r < 4; ++r) {
          float s = sa[mi][ni][r] * SCALE_LOG2E;
          s = (mask_on && gcol > grow0 + r) ? -INFINITY : s;
          sa[mi][ni][r] = s;
        }
      }
#pragma unroll
      for (int r = 0; r < 4; ++r) {
        float mx = fmaxf(fmaxf(sa[mi][0][r], sa[mi][1][r]),
                         fmaxf(sa[mi][2][r], sa[mi][3][r]));
        mx = fmaxf(mx, __shfl_xor(mx, 1));
        mx = fmaxf(mx, __shfl_xor(mx, 2));
        mx = fmaxf(mx, __shfl_xor(mx, 4));
        mx = fmaxf(mx, __shfl_xor(mx, 8));
        const float mold = mrow[mi][r];
        const float mnew = fmaxf(mold, mx);
        const float a = exp2f(mold - mnew);   // 0 on first valid tile
        mrow[mi][r] = mnew;
        alpha[mi][r] = a;
#pragma unroll
        for (int ni = 0; ni < 4; ++ni)
          sa[mi][ni][r] = exp2f(sa[mi][ni][r] - mnew);  // masked -> 0
#pragma unroll
        for (int di = 0; di < 4; ++di) o_acc[mi][di][r] *= a;
      }
      // P: C-layout -> LDS [row][j] (only own wave's rows; no barrier needed)
#pragma unroll
      for (int ni = 0; ni < 4; ++ni)
#pragma unroll
        for (int r = 0; r < 4; ++r)
          Ps[(wave * 32 + mi * 16 + quad * 4 + r) * 72 + ni * 16 + l16] =
              f2bf(sa[mi][ni][r]);
    }

    // ---- O += P V ; row sums l += P . 1 ----
    bf16x8 pf[2][2], vf[4][2];
#pragma unroll
    for (int mi = 0; mi < 2; ++mi)
#pragma unroll
      for (int ks = 0; ks < 2; ++ks)
        pf[mi][ks] = ldfrag(&Ps[(wave * 32 + mi * 16 + l16) * 72 + ks * 32 + quad * 8]);
#pragma unroll
    for (int di = 0; di < 4; ++di)
#pragma unroll
      for (int ks = 0; ks < 2; ++ks)
        vf[di][ks] = ldfrag(&Vts[(di * 16 + l16) * 72 + ks * 32 + quad * 8]);
#pragma unroll
    for (int mi = 0; mi < 2; ++mi) {
      f32x4 rs = f32x4{0.f, 0.f, 0.f, 0.f};
      rs = mfma_bf16(pf[mi][0], ones, rs);
      rs = mfma_bf16(pf[mi][1], ones, rs);
#pragma unroll
      for (int r = 0; r < 4; ++r)
        lrow[mi][r] = lrow[mi][r] * alpha[mi][r] + rs[r];
#pragma unroll
      for (int di = 0; di < 4; ++di) {
        o_acc[mi][di] = mfma_bf16(pf[mi][0], vf[di][0], o_acc[mi][di]);
        o_acc[mi][di] = mfma_bf16(pf[mi][1], vf[di][1], o_acc[mi][di]);
      }
    }
    __syncthreads();  // done reading Ks/Vts before next-iter restage
  }

  // ---- epilogue: O /= l, write bf16 concat layout ----
  u16* Op = Xo + base + (size_t)qt * 128 * E_;
#pragma unroll
  for (int mi = 0; mi < 2; ++mi)
#pragma unroll
    for (int r = 0; r < 4; ++r) {
      const float inv = 1.0f / lrow[mi][r];
      const int row = wave * 32 + mi * 16 + quad * 4 + r;
#pragma unroll
      for (int di = 0; di < 4; ++di)
        Op[(size_t)row * E_ + di * 16 + l16] = f2bf(o_acc[mi][di][r] * inv);
    }
}

// ---------------------------------------------------------------------------
// Host launch. ws layout (bytes):
//   [0,          50331648) qkv bf16 (q,k,v)  -- later reused as Xo
//   [50331648,   56623104) Wt bf16 (Wq,Wk,Wv transformed)
//   [56623104,   58720256) Wp bf16
//   [58720256,  109051904) X bf16 (Xq,Xk,Xv)
// ---------------------------------------------------------------------------
extern "C" void kernel_launch(void* const* d_in, const int* in_sizes, int n_in,
                              void* d_out, int out_size, void* d_ws, size_t ws_size,
                              hipStream_t stream) {
  const float* k_in = (const float*)d_in[0];
  const float* q_in = (const float*)d_in[1];
  const float* v_in = (const float*)d_in[2];
  // d_in[3] = mask: exactly triu(k=1) causal -> computed analytically
  const float* Wk = (const float*)d_in[4];
  const float* Wq = (const float*)d_in[5];
  const float* Wv = (const float*)d_in[6];
  const float* Wp = (const float*)d_in[7];
  const float* bp = (const float*)d_in[8];
  float* out = (float*)d_out;

  char* ws = (char*)d_ws;
  u16* qkvb = (u16*)ws;
  u16* Wt   = (u16*)(ws + 50331648);
  u16* Wpb  = (u16*)(ws + 56623104);
  u16* X    = (u16*)(ws + 58720256);
  u16* Xo   = (u16*)ws;  // alias: qkv bf16 dead after proj GEMM

  cast_qkv_kernel<<<dim3(4096, 3), 256, 0, stream>>>(q_in, k_in, v_in, qkvb);
  prep_weights_kernel<<<dim3(4096, 4), 256, 0, stream>>>(Wq, Wk, Wv, Wp, Wt, Wpb);
  gemm_bt_kernel<0><<<dim3(64, 8, 3), 256, 0, stream>>>(qkvb, Wt, X, nullptr, nullptr);
  attn_kernel<<<dim3(64, 16), 256, 0, stream>>>(X, X + (size_t)MK, X + (size_t)2 * MK, Xo);
  gemm_bt_kernel<1><<<dim3(64, 8, 1), 256, 0, stream>>>(Xo, Wpb, nullptr, out, bp);
}